// Round 10
// baseline (216.672 us; speedup 1.0000x reference)
//
#include <hip/hip_runtime.h>
#include <math.h>

#define BB 4
#define TT 4096
#define CC 768
#define HH 64
#define NN 192   // 3*HH output cols of fused QKV GEMM
#define LDP 72   // padded LDS row stride in bf16 elems
#define GR 32    // rows per qkv_gemm block
#define XSTR 776 // qkv A-tile LDS row stride (97*8 elems, 16B-aligned)

typedef __bf16 bf16x8 __attribute__((ext_vector_type(8)));
typedef float floatx4 __attribute__((ext_vector_type(4)));
typedef unsigned short u16x8 __attribute__((ext_vector_type(8)));

__device__ inline unsigned short f2bf(float f) {
    union { __bf16 b; unsigned short u; } v;
    v.b = (__bf16)f;                      // hw cvt (RTNE) on gfx950
    return v.u;
}

// ---------------- Kernel 0: W prep — fragment-order B + counter zero --------
// wtf[((n_tile*24 + kg)*64 + lane)*8 + j] = W_cat[c][n], n = n_tile*16+(lane&15),
// c = kg*32 + (lane>>4)*8 + j. Also zeroes the BB*64 split-K counters
// (stream order guarantees they're ready before attn_part).
__global__ __launch_bounds__(256) void wprep(const float* __restrict__ Wq,
                                             const float* __restrict__ Wk,
                                             const float* __restrict__ Wv,
                                             unsigned short* __restrict__ wtf,
                                             int* __restrict__ cnt) {
    if (blockIdx.x == 0) cnt[threadIdx.x] = 0;          // BB*64 == 256
    const int idx = blockIdx.x * 256 + threadIdx.x;
    if (idx >= NN * CC) return;
    const int j = idx & 7;
    const int lane = (idx >> 3) & 63;
    const int rest = idx >> 9;              // 0..287
    const int kg = rest % 24;
    const int n_tile = rest / 24;
    const int c = kg * 32 + (lane >> 4) * 8 + j;
    const int n = n_tile * 16 + (lane & 15);
    const float* W = (n < 64) ? Wq : (n < 128) ? Wk : Wv;
    wtf[idx] = f2bf(W[c * HH + (n & 63)]);
}

// ---------------- Kernel 1: fused QKV projection MFMA GEMM ------------------
// 512 blocks x 256 threads. Stage the block's ENTIRE A-tile (32 rows x 768,
// bf16, 48.5 KB) once, ONE barrier, then a barrier-free K-loop: A-frags from
// LDS, B-frags direct from fragment-ordered wtf (coalesced, L2-resident).
__global__ __launch_bounds__(256) void qkv_gemm(const float* __restrict__ x,
                                                const unsigned short* __restrict__ wtf,
                                                unsigned short* __restrict__ qb,
                                                unsigned short* __restrict__ kb,
                                                unsigned short* __restrict__ vbt) {
    __shared__ unsigned short As[GR * XSTR];  // 48.5 KB

    const int tid = threadIdx.x;
    const int w = tid >> 6, lane = tid & 63;
    const int l15 = lane & 15, quad = lane >> 4;
    const int m0 = blockIdx.x * GR;
    const int n0 = w * 48;                    // wave col offset
    const int nt0 = w * 3;                    // wave first col-tile

    const float* xbase = x + (size_t)m0 * CC;
#pragma unroll
    for (int e = 0; e < 12; ++e) {
        const int c = tid + 256 * e;          // 0..3071
        const int r = c / 96, off = (c - r * 96) * 8;
        const float4 v0 = *(const float4*)(xbase + (size_t)c * 8);
        const float4 v1 = *(const float4*)(xbase + (size_t)c * 8 + 4);
        u16x8 pk;
        pk[0] = f2bf(v0.x); pk[1] = f2bf(v0.y); pk[2] = f2bf(v0.z); pk[3] = f2bf(v0.w);
        pk[4] = f2bf(v1.x); pk[5] = f2bf(v1.y); pk[6] = f2bf(v1.z); pk[7] = f2bf(v1.w);
        *(u16x8*)(As + r * XSTR + off) = pk;
    }
    __syncthreads();                          // the ONLY barrier

    floatx4 acc[2][3] = {};
#pragma unroll 4
    for (int step = 0; step < 12; ++step) {
        bf16x8 a0[2], a1[2];
#pragma unroll
        for (int rg = 0; rg < 2; ++rg) {
            const unsigned short* ap = As + (16 * rg + l15) * XSTR + step * 64 + quad * 8;
            a0[rg] = *(const bf16x8*)(ap);
            a1[rg] = *(const bf16x8*)(ap + 32);
        }
#pragma unroll
        for (int j = 0; j < 3; ++j) {
            const unsigned short* bp =
                wtf + ((size_t)((nt0 + j) * 24 + 2 * step) * 64 + lane) * 8;
            const bf16x8 b0 = *(const bf16x8*)(bp);
            const bf16x8 b1 = *(const bf16x8*)(bp + 512);
#pragma unroll
            for (int rg = 0; rg < 2; ++rg) {
                acc[rg][j] = __builtin_amdgcn_mfma_f32_16x16x32_bf16(a0[rg], b0, acc[rg][j], 0, 0, 0);
                acc[rg][j] = __builtin_amdgcn_mfma_f32_16x16x32_bf16(a1[rg], b1, acc[rg][j], 0, 0, 0);
            }
        }
    }

    const int b = m0 >> 12;
#pragma unroll
    for (int j = 0; j < 3; ++j) {
        const int n = n0 + j * 16 + l15;
        const int mid = n >> 6;                  // 0=Q,1=K,2=V
        const int h = n & 63;
#pragma unroll
        for (int rg = 0; rg < 2; ++rg) {
            const int tloc = (m0 & (TT - 1)) + 16 * rg + quad * 4;
            if (mid == 2) {
                ushort4 pk;
                pk.x = f2bf(acc[rg][j][0]); pk.y = f2bf(acc[rg][j][1]);
                pk.z = f2bf(acc[rg][j][2]); pk.w = f2bf(acc[rg][j][3]);
                *(ushort4*)(vbt + ((size_t)b * HH + h) * TT + tloc) = pk;
            } else {
                unsigned short* dst = (mid == 0) ? qb : kb;
#pragma unroll
                for (int r = 0; r < 4; ++r)
                    dst[(size_t)(m0 + 16 * rg + quad * 4 + r) * HH + h] = f2bf(acc[rg][j][r]);
            }
        }
    }
}

// ------------- Kernel 2: flash attention split-K + FUSED merge --------------
// 128 threads = 2 waves; wave owns 32 q-rows (two A-fragments / K-frag read).
// Heavy-first chunk order, no online max (|s| bounded). After writing
// partials: device fence + atomic counter; the LAST finisher of a q-tile
// reduces all its chunks directly to `out` (no separate merge kernel;
// merges overlap still-running chunks).
template<int CH>
__global__ __launch_bounds__(128) void attn_part(const unsigned short* __restrict__ qb,
                                                 const unsigned short* __restrict__ kb,
                                                 const unsigned short* __restrict__ vbt,
                                                 float* __restrict__ Opart,
                                                 float* __restrict__ lsum,
                                                 int* __restrict__ cnt,
                                                 float* __restrict__ out) {
    __shared__ unsigned short Ks[64 * LDP];
    __shared__ unsigned short VTs[64 * LDP];
    __shared__ unsigned short Ps[2][32 * LDP];
    __shared__ int last_flag;

    constexpr int NG = 64 / CH;
    constexpr int TOTB = CH * (NG * (NG + 1)) / 2;

    const int b = blockIdx.x & 3;
    int rem = TOTB - 1 - (blockIdx.x >> 2);           // heavy-first
    int g = 0;
    while (rem >= CH * (g + 1)) { rem -= CH * (g + 1); ++g; }
    const int qt = g * CH + rem / (g + 1);
    const int ch = rem - (rem / (g + 1)) * (g + 1);

    const int q0  = qt * 64;
    const int tid = threadIdx.x;
    const int w = tid >> 6, lane = tid & 63;
    const int l15 = lane & 15, quad = lane >> 4;

    const unsigned short* Qb  = qb  + (size_t)b * TT * HH;
    const unsigned short* Kb  = kb  + (size_t)b * TT * HH;
    const unsigned short* VTb = vbt + (size_t)b * HH * TT;

    bf16x8 qf0[2], qf1[2];
#pragma unroll
    for (int rg = 0; rg < 2; ++rg) {
        const unsigned short* qp = Qb + (size_t)(q0 + 32 * w + 16 * rg + l15) * HH + quad * 8;
        qf0[rg] = *(const bf16x8*)(qp);
        qf1[rg] = *(const bf16x8*)(qp + 32);
    }

    floatx4 O[2][4] = {};
    floatx4 lacc[2] = {};

    const int kt0 = ch * CH;
    const int kt1 = min(kt0 + CH, qt + 1);
    for (int kt = kt0; kt < kt1; ++kt) {
        __syncthreads();
        const unsigned short* Kt = Kb + (size_t)(kt * 64) * HH;
        const unsigned short* Vt = VTb + kt * 64;
#pragma unroll
        for (int e = 0; e < 4; ++e) {
            const int chunk = tid + 128 * e;          // 0..511
            const int r = chunk >> 3, c0 = (chunk & 7) * 8;
            *(u16x8*)(Ks + r * LDP + c0)  = *(const u16x8*)(Kt + r * HH + c0);
            *(u16x8*)(VTs + r * LDP + c0) = *(const u16x8*)(Vt + (size_t)r * TT + c0);
        }
        __syncthreads();

        floatx4 s[2][4];
#pragma unroll
        for (int ki = 0; ki < 4; ++ki) {
            const unsigned short* kp = Ks + (16 * ki + l15) * LDP + quad * 8;
            const bf16x8 kf0 = *(const bf16x8*)(kp);
            const bf16x8 kf1 = *(const bf16x8*)(kp + 32);
#pragma unroll
            for (int rg = 0; rg < 2; ++rg) {
                floatx4 c = {};
                c = __builtin_amdgcn_mfma_f32_16x16x32_bf16(qf0[rg], kf0, c, 0, 0, 0);
                c = __builtin_amdgcn_mfma_f32_16x16x32_bf16(qf1[rg], kf1, c, 0, 0, 0);
                s[rg][ki] = c * 0.125f;
            }
        }

        if (kt == qt) {
#pragma unroll
            for (int rg = 0; rg < 2; ++rg)
#pragma unroll
                for (int ki = 0; ki < 4; ++ki)
#pragma unroll
                    for (int r = 0; r < 4; ++r) {
                        const int kloc = 16 * ki + l15;
                        const int qloc = 32 * w + 16 * rg + quad * 4 + r;
                        if (kloc > qloc) s[rg][ki][r] = -INFINITY;
                    }
        }

#pragma unroll
        for (int rg = 0; rg < 2; ++rg)
#pragma unroll
            for (int ki = 0; ki < 4; ++ki)
#pragma unroll
                for (int r = 0; r < 4; ++r) {
                    const float p = __expf(s[rg][ki][r]);
                    s[rg][ki][r] = p;
                    lacc[rg][r] += p;
                }

        unsigned short* Pw = Ps[w];
#pragma unroll
        for (int rg = 0; rg < 2; ++rg)
#pragma unroll
            for (int ki = 0; ki < 4; ++ki)
#pragma unroll
                for (int r = 0; r < 4; ++r)
                    Pw[(16 * rg + quad * 4 + r) * LDP + 16 * ki + l15] = f2bf(s[rg][ki][r]);

        bf16x8 pf0[2], pf1[2];
#pragma unroll
        for (int rg = 0; rg < 2; ++rg) {
            const unsigned short* pp = Pw + (16 * rg + l15) * LDP + quad * 8;
            pf0[rg] = *(const bf16x8*)(pp);
            pf1[rg] = *(const bf16x8*)(pp + 32);
        }
#pragma unroll
        for (int di = 0; di < 4; ++di) {
            const unsigned short* vp = VTs + (16 * di + l15) * LDP + quad * 8;
            const bf16x8 vf0 = *(const bf16x8*)(vp);
            const bf16x8 vf1 = *(const bf16x8*)(vp + 32);
#pragma unroll
            for (int rg = 0; rg < 2; ++rg) {
                O[rg][di] = __builtin_amdgcn_mfma_f32_16x16x32_bf16(pf0[rg], vf0, O[rg][di], 0, 0, 0);
                O[rg][di] = __builtin_amdgcn_mfma_f32_16x16x32_bf16(pf1[rg], vf1, O[rg][di], 0, 0, 0);
            }
        }
    }

    // ---- write partials ----
    const int pbase = ((b * 64 + qt) * NG + ch) * 64;
#pragma unroll
    for (int rg = 0; rg < 2; ++rg) {
        float l_r[4];
#pragma unroll
        for (int r = 0; r < 4; ++r) {
            float v = lacc[rg][r];
#pragma unroll
            for (int msk = 8; msk >= 1; msk >>= 1) v += __shfl_xor(v, msk, 64);
            l_r[r] = v;
        }
        float* Op = Opart + (size_t)(pbase + 32 * w + 16 * rg) * HH;
#pragma unroll
        for (int di = 0; di < 4; ++di)
#pragma unroll
            for (int r = 0; r < 4; ++r)
                Op[(quad * 4 + r) * HH + 16 * di + l15] = O[rg][di][r];
        if (l15 == 0) {
#pragma unroll
            for (int r = 0; r < 4; ++r)
                lsum[pbase + 32 * w + 16 * rg + quad * 4 + r] = l_r[r];
        }
    }

    // ---- last-block-done fused merge ----
    __threadfence();                                  // release partials
    if (tid == 0) {
        const int done = atomicAdd(&cnt[b * 64 + qt], 1);
        last_flag = (done == qt / CH);                // nchunk-1
    }
    __syncthreads();
    if (!last_flag) return;
    __threadfence();                                  // acquire partials

    const int nchunk = qt / CH + 1;
    const int rloc = tid >> 1;                        // 0..63
    const int h2 = (tid & 1) * 32;                    // dim half
    const int rowbase = (b * 64 + qt) * NG;

    float L = 0.f;
    for (int c = 0; c < nchunk; ++c) L += lsum[rowbase * 64 + c * 64 + rloc];

    floatx4 a4[8] = {};
    for (int c = 0; c < nchunk; ++c) {
        const floatx4* src = (const floatx4*)(Opart +
            (size_t)(rowbase + c) * 64 * HH + (size_t)rloc * HH + h2);
#pragma unroll
        for (int k = 0; k < 8; ++k) a4[k] += src[k];
    }
    const float inv = 1.f / L;
    floatx4* dst = (floatx4*)(out + ((size_t)b * TT + q0 + rloc) * HH + h2);
#pragma unroll
    for (int k = 0; k < 8; ++k) dst[k] = a4[k] * inv;
}

// ------------- Fallback: single-pass attention ------------------------------
__global__ __launch_bounds__(256) void attn_full(const unsigned short* __restrict__ qb,
                                                 const unsigned short* __restrict__ kb,
                                                 const unsigned short* __restrict__ vbt,
                                                 float* __restrict__ out) {
    __shared__ unsigned short Ks[64 * LDP];
    __shared__ unsigned short VTs[64 * LDP];
    __shared__ unsigned short Ps[4][16 * LDP];

    const int b   = blockIdx.x >> 6;
    const int qt  = blockIdx.x & 63;
    const int q0  = qt * 64;
    const int tid = threadIdx.x;
    const int w = tid >> 6, lane = tid & 63;
    const int l15 = lane & 15, quad = lane >> 4;

    const unsigned short* Qb  = qb  + (size_t)b * TT * HH;
    const unsigned short* Kb  = kb  + (size_t)b * TT * HH;
    const unsigned short* VTb = vbt + (size_t)b * HH * TT;

    const int qrow = q0 + 16 * w + l15;
    const bf16x8 qf0 = *(const bf16x8*)(Qb + (size_t)qrow * HH + quad * 8);
    const bf16x8 qf1 = *(const bf16x8*)(Qb + (size_t)qrow * HH + 32 + quad * 8);

    floatx4 O[4] = {};
    floatx4 lacc = {0.f, 0.f, 0.f, 0.f};

    for (int kt = 0; kt <= qt; ++kt) {
        __syncthreads();
        const unsigned short* Kt = Kb + (size_t)(kt * 64) * HH;
        const unsigned short* Vt = VTb + kt * 64;
#pragma unroll
        for (int e = 0; e < 2; ++e) {
            const int chunk = tid + 256 * e;
            const int r = chunk >> 3, c0 = (chunk & 7) * 8;
            *(u16x8*)(Ks + r * LDP + c0)  = *(const u16x8*)(Kt + r * HH + c0);
            *(u16x8*)(VTs + r * LDP + c0) = *(const u16x8*)(Vt + (size_t)r * TT + c0);
        }
        __syncthreads();

        floatx4 s[4];
#pragma unroll
        for (int ki = 0; ki < 4; ++ki) {
            const bf16x8 kf0 = *(const bf16x8*)(Ks + (16 * ki + l15) * LDP + quad * 8);
            const bf16x8 kf1 = *(const bf16x8*)(Ks + (16 * ki + l15) * LDP + 32 + quad * 8);
            floatx4 c = {};
            c = __builtin_amdgcn_mfma_f32_16x16x32_bf16(qf0, kf0, c, 0, 0, 0);
            c = __builtin_amdgcn_mfma_f32_16x16x32_bf16(qf1, kf1, c, 0, 0, 0);
            s[ki] = c * 0.125f;
        }
        if (kt == qt) {
#pragma unroll
            for (int ki = 0; ki < 4; ++ki)
#pragma unroll
                for (int r = 0; r < 4; ++r)
                    if (16 * ki + l15 > 16 * w + quad * 4 + r) s[ki][r] = -INFINITY;
        }
#pragma unroll
        for (int ki = 0; ki < 4; ++ki)
#pragma unroll
            for (int r = 0; r < 4; ++r) {
                const float p = __expf(s[ki][r]);
                s[ki][r] = p; lacc[r] += p;
            }

        unsigned short* Pw = Ps[w];
#pragma unroll
        for (int ki = 0; ki < 4; ++ki)
#pragma unroll
            for (int r = 0; r < 4; ++r)
                Pw[(quad * 4 + r) * LDP + 16 * ki + l15] = f2bf(s[ki][r]);

        const bf16x8 pf0 = *(const bf16x8*)(Pw + l15 * LDP + quad * 8);
        const bf16x8 pf1 = *(const bf16x8*)(Pw + l15 * LDP + 32 + quad * 8);
#pragma unroll
        for (int di = 0; di < 4; ++di) {
            const bf16x8 vf0 = *(const bf16x8*)(VTs + (16 * di + l15) * LDP + quad * 8);
            const bf16x8 vf1 = *(const bf16x8*)(VTs + (16 * di + l15) * LDP + 32 + quad * 8);
            O[di] = __builtin_amdgcn_mfma_f32_16x16x32_bf16(pf0, vf0, O[di], 0, 0, 0);
            O[di] = __builtin_amdgcn_mfma_f32_16x16x32_bf16(pf1, vf1, O[di], 0, 0, 0);
        }
    }
    float l_r[4];
#pragma unroll
    for (int r = 0; r < 4; ++r) {
        float v = lacc[r];
#pragma unroll
        for (int msk = 8; msk >= 1; msk >>= 1) v += __shfl_xor(v, msk, 64);
        l_r[r] = v;
    }
    float* outp = out + ((size_t)b * TT + q0 + 16 * w) * HH;
#pragma unroll
    for (int di = 0; di < 4; ++di)
#pragma unroll
        for (int r = 0; r < 4; ++r)
            outp[(quad * 4 + r) * HH + 16 * di + l15] = O[di][r] / l_r[r];
}

extern "C" void kernel_launch(void* const* d_in, const int* in_sizes, int n_in,
                              void* d_out, int out_size, void* d_ws, size_t ws_size,
                              hipStream_t stream) {
    const float* x  = (const float*)d_in[0];
    const float* Wq = (const float*)d_in[1];
    const float* Wk = (const float*)d_in[2];
    const float* Wv = (const float*)d_in[3];
    float* out = (float*)d_out;

    const size_t nQKV = (size_t)BB * TT * HH;           // 1 Mi elems
    unsigned short* qb  = (unsigned short*)d_ws;
    unsigned short* kb  = qb + nQKV;
    unsigned short* vbt = kb + nQKV;
    unsigned short* wtf = vbt + nQKV;                   // NN*CC ushorts
    float* Opart = (float*)(wtf + (size_t)NN * CC);

    const size_t prows8  = (size_t)BB * 64 * 8 * 64;
    const size_t prows16 = (size_t)BB * 64 * 4 * 64;
    float* lsum8  = Opart + prows8 * HH;
    float* lsum16 = Opart + prows16 * HH;
    int* cnt8  = (int*)(lsum8  + prows8);
    int* cnt16 = (int*)(lsum16 + prows16);
    const size_t need8  = (size_t)((char*)(cnt8  + BB * 64) - (char*)d_ws);
    const size_t need16 = (size_t)((char*)(cnt16 + BB * 64) - (char*)d_ws);

    if (ws_size >= need8) {
        wprep<<<(NN * CC + 255) / 256, 256, 0, stream>>>(Wq, Wk, Wv, wtf, cnt8);
        qkv_gemm<<<(BB * TT) / GR, 256, 0, stream>>>(x, wtf, qb, kb, vbt);
        attn_part<8><<<BB * 288, 128, 0, stream>>>(qb, kb, vbt, Opart, lsum8, cnt8, out);
    } else if (ws_size >= need16) {
        wprep<<<(NN * CC + 255) / 256, 256, 0, stream>>>(Wq, Wk, Wv, wtf, cnt16);
        qkv_gemm<<<(BB * TT) / GR, 256, 0, stream>>>(x, wtf, qb, kb, vbt);
        attn_part<16><<<BB * 160, 128, 0, stream>>>(qb, kb, vbt, Opart, lsum16, cnt16, out);
    } else {
        wprep<<<(NN * CC + 255) / 256, 256, 0, stream>>>(Wq, Wk, Wv, wtf, cnt8);
        qkv_gemm<<<(BB * TT) / GR, 256, 0, stream>>>(x, wtf, qb, kb, vbt);
        attn_full<<<BB * (TT / 64), 256, 0, stream>>>(qb, kb, vbt, out);
    }
}

// Round 11
// 134.273 us; speedup vs baseline: 1.6137x; 1.6137x over previous
//
#include <hip/hip_runtime.h>
#include <math.h>

#define BB 4
#define TT 4096
#define CC 768
#define HH 64
#define NN 192   // 3*HH output cols of fused QKV GEMM
#define LDP 72   // padded LDS row stride in bf16 elems
#define GR 16    // rows per qkv_gemm block -> 1024 blocks = 4 blocks/CU
#define BKK 64   // K per staging step

typedef __bf16 bf16x8 __attribute__((ext_vector_type(8)));
typedef float floatx4 __attribute__((ext_vector_type(4)));
typedef unsigned short u16x8 __attribute__((ext_vector_type(8)));

__device__ inline unsigned short f2bf(float f) {
    union { __bf16 b; unsigned short u; } v;
    v.b = (__bf16)f;                      // hw cvt (RTNE) on gfx950
    return v.u;
}

// ---------------- Kernel 0: W prep — fragment-order B ----------------------
// wtf[((n_tile*24 + kg)*64 + lane)*8 + j] = W_cat[c][n], n = n_tile*16+(lane&15),
// c = kg*32 + (lane>>4)*8 + j. B-frag load = coalesced 1KB dwordx4.
__global__ __launch_bounds__(256) void wprep(const float* __restrict__ Wq,
                                             const float* __restrict__ Wk,
                                             const float* __restrict__ Wv,
                                             unsigned short* __restrict__ wtf) {
    const int idx = blockIdx.x * 256 + threadIdx.x;
    if (idx >= NN * CC) return;
    const int j = idx & 7;
    const int lane = (idx >> 3) & 63;
    const int rest = idx >> 9;              // 0..287
    const int kg = rest % 24;
    const int n_tile = rest / 24;
    const int c = kg * 32 + (lane >> 4) * 8 + j;
    const int n = n_tile * 16 + (lane & 15);
    const float* W = (n < 64) ? Wq : (n < 128) ? Wk : Wv;
    wtf[idx] = f2bf(W[c * HH + (n & 63)]);
}

// ---------------- Kernel 1: fused QKV projection MFMA GEMM ------------------
// 1024 blocks x 256 threads (4 blocks/CU — grid no longer caps occupancy).
// Block: 16 rows x 192 cols; wave w: 16 rows x 48 cols (3 col-tiles,
// 6 MFMA/step). A: LDS-staged from x with register prefetch; B: direct
// coalesced 1KB loads from fragment-ordered wtf (L2/L1-resident).
__global__ __launch_bounds__(256) void qkv_gemm(const float* __restrict__ x,
                                                const unsigned short* __restrict__ wtf,
                                                unsigned short* __restrict__ qb,
                                                unsigned short* __restrict__ kb,
                                                unsigned short* __restrict__ vbt) {
    __shared__ unsigned short As[GR * LDP];   // 2.3 KB

    const int tid = threadIdx.x;
    const int w = tid >> 6, lane = tid & 63;
    const int l15 = lane & 15, quad = lane >> 4;
    const int m0 = blockIdx.x * GR;
    const int n0 = w * 48;                    // wave col offset
    const int nt0 = w * 3;                    // wave first col-tile

    // A staging: thread t -> row r = t>>4 (16 rows), k-offset (t&15)*4
    const int ar = tid >> 4;
    const int akoff = (tid & 15) * 4;
    const float* xp = x + (size_t)(m0 + ar) * CC + akoff;

    floatx4 acc[3] = {};

    float4 pa = *(const float4*)(xp);         // prefetch step 0

    for (int step = 0; step < 12; ++step) {
        __syncthreads();                      // previous As fully consumed
        ushort4 pk;
        pk.x = f2bf(pa.x); pk.y = f2bf(pa.y);
        pk.z = f2bf(pa.z); pk.w = f2bf(pa.w);
        *(ushort4*)(As + ar * LDP + akoff) = pk;
        __syncthreads();

        if (step < 11)                        // prefetch next (overlaps MFMAs)
            pa = *(const float4*)(xp + (step + 1) * BKK);

        const bf16x8 a0 = *(const bf16x8*)(As + l15 * LDP + quad * 8);
        const bf16x8 a1 = *(const bf16x8*)(As + l15 * LDP + 32 + quad * 8);
#pragma unroll
        for (int j = 0; j < 3; ++j) {
            const unsigned short* bp =
                wtf + ((size_t)((nt0 + j) * 24 + 2 * step) * 64 + lane) * 8;
            const bf16x8 b0 = *(const bf16x8*)(bp);
            const bf16x8 b1 = *(const bf16x8*)(bp + 512);
            acc[j] = __builtin_amdgcn_mfma_f32_16x16x32_bf16(a0, b0, acc[j], 0, 0, 0);
            acc[j] = __builtin_amdgcn_mfma_f32_16x16x32_bf16(a1, b1, acc[j], 0, 0, 0);
        }
    }

    const int b = m0 >> 12;
    const int tloc = (m0 & (TT - 1)) + quad * 4;
#pragma unroll
    for (int j = 0; j < 3; ++j) {
        const int n = n0 + j * 16 + l15;
        const int mid = n >> 6;                  // 0=Q,1=K,2=V
        const int h = n & 63;
        if (mid == 2) {
            ushort4 pk;
            pk.x = f2bf(acc[j][0]); pk.y = f2bf(acc[j][1]);
            pk.z = f2bf(acc[j][2]); pk.w = f2bf(acc[j][3]);
            *(ushort4*)(vbt + ((size_t)b * HH + h) * TT + tloc) = pk;
        } else {
            unsigned short* dst = (mid == 0) ? qb : kb;
#pragma unroll
            for (int r = 0; r < 4; ++r)
                dst[(size_t)(m0 + quad * 4 + r) * HH + h] = f2bf(acc[j][r]);
        }
    }
}

// ------------- Kernel 2a: flash attention phase 1 (split-K partials) --------
// R7-proven: LDS-staged, CH tiles/chunk, heavy-first, no online max
// (|s| O(1)-bounded -> unnormalized exp is fp32-safe), 256 threads.
template<int CH>
__global__ __launch_bounds__(256) void attn_part(const unsigned short* __restrict__ qb,
                                                 const unsigned short* __restrict__ kb,
                                                 const unsigned short* __restrict__ vbt,
                                                 float* __restrict__ Opart,
                                                 float* __restrict__ lsum) {
    __shared__ unsigned short Ks[64 * LDP];
    __shared__ unsigned short VTs[64 * LDP];
    __shared__ unsigned short Ps[4][16 * LDP];

    constexpr int NG = 64 / CH;
    constexpr int TOTB = CH * (NG * (NG + 1)) / 2;

    const int b = blockIdx.x & 3;
    int rem = TOTB - 1 - (blockIdx.x >> 2);           // heavy-first
    int g = 0;
    while (rem >= CH * (g + 1)) { rem -= CH * (g + 1); ++g; }
    const int qt = g * CH + rem / (g + 1);
    const int ch = rem - (rem / (g + 1)) * (g + 1);

    const int q0  = qt * 64;
    const int tid = threadIdx.x;
    const int w = tid >> 6, lane = tid & 63;
    const int l15 = lane & 15, quad = lane >> 4;

    const unsigned short* Qb  = qb  + (size_t)b * TT * HH;
    const unsigned short* Kb  = kb  + (size_t)b * TT * HH;
    const unsigned short* VTb = vbt + (size_t)b * HH * TT;

    const int qrow = q0 + 16 * w + l15;
    const bf16x8 qf0 = *(const bf16x8*)(Qb + (size_t)qrow * HH + quad * 8);
    const bf16x8 qf1 = *(const bf16x8*)(Qb + (size_t)qrow * HH + 32 + quad * 8);

    floatx4 O[4] = {};
    floatx4 lacc = {0.f, 0.f, 0.f, 0.f};

    const int kt0 = ch * CH;
    const int kt1 = min(kt0 + CH, qt + 1);
    for (int kt = kt0; kt < kt1; ++kt) {
        __syncthreads();
        const unsigned short* Kt = Kb + (size_t)(kt * 64) * HH;
        const unsigned short* Vt = VTb + kt * 64;
#pragma unroll
        for (int e = 0; e < 2; ++e) {
            const int chunk = tid + 256 * e;
            const int r = chunk >> 3, c0 = (chunk & 7) * 8;
            *(u16x8*)(Ks + r * LDP + c0)  = *(const u16x8*)(Kt + r * HH + c0);
            *(u16x8*)(VTs + r * LDP + c0) = *(const u16x8*)(Vt + (size_t)r * TT + c0);
        }
        __syncthreads();

        floatx4 s[4];
#pragma unroll
        for (int ki = 0; ki < 4; ++ki) {
            const bf16x8 kf0 = *(const bf16x8*)(Ks + (16 * ki + l15) * LDP + quad * 8);
            const bf16x8 kf1 = *(const bf16x8*)(Ks + (16 * ki + l15) * LDP + 32 + quad * 8);
            floatx4 c = {};
            c = __builtin_amdgcn_mfma_f32_16x16x32_bf16(qf0, kf0, c, 0, 0, 0);
            c = __builtin_amdgcn_mfma_f32_16x16x32_bf16(qf1, kf1, c, 0, 0, 0);
            s[ki] = c * 0.125f;
        }

        if (kt == qt) {
#pragma unroll
            for (int ki = 0; ki < 4; ++ki)
#pragma unroll
                for (int r = 0; r < 4; ++r) {
                    const int kloc = 16 * ki + l15;
                    const int qloc = 16 * w + quad * 4 + r;
                    if (kloc > qloc) s[ki][r] = -INFINITY;
                }
        }

#pragma unroll
        for (int ki = 0; ki < 4; ++ki)
#pragma unroll
            for (int r = 0; r < 4; ++r) {
                const float p = __expf(s[ki][r]);
                s[ki][r] = p;
                lacc[r] += p;
            }

        unsigned short* Pw = Ps[w];
#pragma unroll
        for (int ki = 0; ki < 4; ++ki)
#pragma unroll
            for (int r = 0; r < 4; ++r)
                Pw[(quad * 4 + r) * LDP + 16 * ki + l15] = f2bf(s[ki][r]);

        const bf16x8 pf0 = *(const bf16x8*)(Pw + l15 * LDP + quad * 8);
        const bf16x8 pf1 = *(const bf16x8*)(Pw + l15 * LDP + 32 + quad * 8);
#pragma unroll
        for (int di = 0; di < 4; ++di) {
            const bf16x8 vf0 = *(const bf16x8*)(VTs + (16 * di + l15) * LDP + quad * 8);
            const bf16x8 vf1 = *(const bf16x8*)(VTs + (16 * di + l15) * LDP + 32 + quad * 8);
            O[di] = __builtin_amdgcn_mfma_f32_16x16x32_bf16(pf0, vf0, O[di], 0, 0, 0);
            O[di] = __builtin_amdgcn_mfma_f32_16x16x32_bf16(pf1, vf1, O[di], 0, 0, 0);
        }
    }

    float l_r[4];
#pragma unroll
    for (int r = 0; r < 4; ++r) {
        float v = lacc[r];
#pragma unroll
        for (int msk = 8; msk >= 1; msk >>= 1) v += __shfl_xor(v, msk, 64);
        l_r[r] = v;
    }

    const int pbase = ((b * 64 + qt) * NG + ch) * 64;
    float* Op = Opart + (size_t)pbase * HH + 16 * w * HH;
#pragma unroll
    for (int di = 0; di < 4; ++di)
#pragma unroll
        for (int r = 0; r < 4; ++r)
            Op[(quad * 4 + r) * HH + 16 * di + l15] = O[di][r];
    if (l15 == 0) {
#pragma unroll
        for (int r = 0; r < 4; ++r)
            lsum[pbase + 16 * w + quad * 4 + r] = l_r[r];
    }
}

// ------------- Kernel 2b: merge partials (plain sum) ------------------------
template<int CH>
__global__ __launch_bounds__(256) void attn_merge(const float* __restrict__ Opart,
                                                  const float* __restrict__ lsum,
                                                  float* __restrict__ out) {
    constexpr int NG = 64 / CH;
    const int g = blockIdx.x * 256 + threadIdx.x;   // row*64 + d
    const int row = g >> 6, d = g & 63;
    const int b = row >> 12, t = row & (TT - 1);
    const int qt = t >> 6, rloc = t & 63;
    const int nchunk = qt / CH + 1;
    const int pbase = ((b * 64 + qt) * NG) * 64 + rloc;

    float O = 0.f, L = 0.f;
#pragma unroll 4
    for (int c = 0; c < nchunk; ++c) {
        const int idx = pbase + c * 64;
        L += lsum[idx];
        O += Opart[(size_t)idx * HH + d];
    }
    out[(size_t)row * HH + d] = O / L;
}

// ------------- Fallback: single-pass attention ------------------------------
__global__ __launch_bounds__(256) void attn_full(const unsigned short* __restrict__ qb,
                                                 const unsigned short* __restrict__ kb,
                                                 const unsigned short* __restrict__ vbt,
                                                 float* __restrict__ out) {
    __shared__ unsigned short Ks[64 * LDP];
    __shared__ unsigned short VTs[64 * LDP];
    __shared__ unsigned short Ps[4][16 * LDP];

    const int b   = blockIdx.x >> 6;
    const int qt  = blockIdx.x & 63;
    const int q0  = qt * 64;
    const int tid = threadIdx.x;
    const int w = tid >> 6, lane = tid & 63;
    const int l15 = lane & 15, quad = lane >> 4;

    const unsigned short* Qb  = qb  + (size_t)b * TT * HH;
    const unsigned short* Kb  = kb  + (size_t)b * TT * HH;
    const unsigned short* VTb = vbt + (size_t)b * HH * TT;

    const int qrow = q0 + 16 * w + l15;
    const bf16x8 qf0 = *(const bf16x8*)(Qb + (size_t)qrow * HH + quad * 8);
    const bf16x8 qf1 = *(const bf16x8*)(Qb + (size_t)qrow * HH + 32 + quad * 8);

    floatx4 O[4] = {};
    floatx4 lacc = {0.f, 0.f, 0.f, 0.f};

    for (int kt = 0; kt <= qt; ++kt) {
        __syncthreads();
        const unsigned short* Kt = Kb + (size_t)(kt * 64) * HH;
        const unsigned short* Vt = VTb + kt * 64;
#pragma unroll
        for (int e = 0; e < 2; ++e) {
            const int chunk = tid + 256 * e;
            const int r = chunk >> 3, c0 = (chunk & 7) * 8;
            *(u16x8*)(Ks + r * LDP + c0)  = *(const u16x8*)(Kt + r * HH + c0);
            *(u16x8*)(VTs + r * LDP + c0) = *(const u16x8*)(Vt + (size_t)r * TT + c0);
        }
        __syncthreads();

        floatx4 s[4];
#pragma unroll
        for (int ki = 0; ki < 4; ++ki) {
            const bf16x8 kf0 = *(const bf16x8*)(Ks + (16 * ki + l15) * LDP + quad * 8);
            const bf16x8 kf1 = *(const bf16x8*)(Ks + (16 * ki + l15) * LDP + 32 + quad * 8);
            floatx4 c = {};
            c = __builtin_amdgcn_mfma_f32_16x16x32_bf16(qf0, kf0, c, 0, 0, 0);
            c = __builtin_amdgcn_mfma_f32_16x16x32_bf16(qf1, kf1, c, 0, 0, 0);
            s[ki] = c * 0.125f;
        }
        if (kt == qt) {
#pragma unroll
            for (int ki = 0; ki < 4; ++ki)
#pragma unroll
                for (int r = 0; r < 4; ++r)
                    if (16 * ki + l15 > 16 * w + quad * 4 + r) s[ki][r] = -INFINITY;
        }
#pragma unroll
        for (int ki = 0; ki < 4; ++ki)
#pragma unroll
            for (int r = 0; r < 4; ++r) {
                const float p = __expf(s[ki][r]);
                s[ki][r] = p; lacc[r] += p;
            }

        unsigned short* Pw = Ps[w];
#pragma unroll
        for (int ki = 0; ki < 4; ++ki)
#pragma unroll
            for (int r = 0; r < 4; ++r)
                Pw[(quad * 4 + r) * LDP + 16 * ki + l15] = f2bf(s[ki][r]);

        const bf16x8 pf0 = *(const bf16x8*)(Pw + l15 * LDP + quad * 8);
        const bf16x8 pf1 = *(const bf16x8*)(Pw + l15 * LDP + 32 + quad * 8);
#pragma unroll
        for (int di = 0; di < 4; ++di) {
            const bf16x8 vf0 = *(const bf16x8*)(VTs + (16 * di + l15) * LDP + quad * 8);
            const bf16x8 vf1 = *(const bf16x8*)(VTs + (16 * di + l15) * LDP + 32 + quad * 8);
            O[di] = __builtin_amdgcn_mfma_f32_16x16x32_bf16(pf0, vf0, O[di], 0, 0, 0);
            O[di] = __builtin_amdgcn_mfma_f32_16x16x32_bf16(pf1, vf1, O[di], 0, 0, 0);
        }
    }
    float l_r[4];
#pragma unroll
    for (int r = 0; r < 4; ++r) {
        float v = lacc[r];
#pragma unroll
        for (int msk = 8; msk >= 1; msk >>= 1) v += __shfl_xor(v, msk, 64);
        l_r[r] = v;
    }
    float* outp = out + ((size_t)b * TT + q0 + 16 * w) * HH;
#pragma unroll
    for (int di = 0; di < 4; ++di)
#pragma unroll
        for (int r = 0; r < 4; ++r)
            outp[(quad * 4 + r) * HH + 16 * di + l15] = O[di][r] / l_r[r];
}

extern "C" void kernel_launch(void* const* d_in, const int* in_sizes, int n_in,
                              void* d_out, int out_size, void* d_ws, size_t ws_size,
                              hipStream_t stream) {
    const float* x  = (const float*)d_in[0];
    const float* Wq = (const float*)d_in[1];
    const float* Wk = (const float*)d_in[2];
    const float* Wv = (const float*)d_in[3];
    float* out = (float*)d_out;

    const size_t nQKV = (size_t)BB * TT * HH;           // 1 Mi elems
    unsigned short* qb  = (unsigned short*)d_ws;
    unsigned short* kb  = qb + nQKV;
    unsigned short* vbt = kb + nQKV;
    unsigned short* wtf = vbt + nQKV;                   // NN*CC ushorts
    float* Opart = (float*)(wtf + (size_t)NN * CC);

    const size_t prows8  = (size_t)BB * 64 * 8 * 64;
    const size_t prows16 = (size_t)BB * 64 * 4 * 64;
    float* lsum8  = Opart + prows8 * HH;
    float* lsum16 = Opart + prows16 * HH;
    const size_t need8  = (size_t)((char*)(lsum8  + prows8)  - (char*)d_ws);
    const size_t need16 = (size_t)((char*)(lsum16 + prows16) - (char*)d_ws);

    wprep<<<(NN * CC + 255) / 256, 256, 0, stream>>>(Wq, Wk, Wv, wtf);
    qkv_gemm<<<(BB * TT) / GR, 256, 0, stream>>>(x, wtf, qb, kb, vbt);
    if (ws_size >= need8) {
        attn_part<8><<<BB * 288, 256, 0, stream>>>(qb, kb, vbt, Opart, lsum8);
        attn_merge<8><<<(BB * TT * HH) / 256, 256, 0, stream>>>(Opart, lsum8, out);
    } else if (ws_size >= need16) {
        attn_part<16><<<BB * 160, 256, 0, stream>>>(qb, kb, vbt, Opart, lsum16);
        attn_merge<16><<<(BB * TT * HH) / 256, 256, 0, stream>>>(Opart, lsum16, out);
    } else {
        attn_full<<<BB * (TT / 64), 256, 0, stream>>>(qb, kb, vbt, out);
    }
}

// Round 12
// 130.391 us; speedup vs baseline: 1.6617x; 1.0298x over previous
//
#include <hip/hip_runtime.h>
#include <math.h>

#define BB 4
#define TT 4096
#define CC 768
#define HH 64
#define NN 192   // 3*HH output cols of fused QKV GEMM
#define LDP 72   // padded LDS row stride in bf16 elems
#define GR 32    // rows per qkv_gemm block
#define XSTR 776 // qkv A-tile LDS row stride (97*8 elems, 16B-aligned)
#define SC2 0.180336880f   // 0.125 * log2(e): QK scale folded with exp->exp2

typedef __bf16 bf16x8 __attribute__((ext_vector_type(8)));
typedef float floatx4 __attribute__((ext_vector_type(4)));
typedef unsigned short u16x8 __attribute__((ext_vector_type(8)));

__device__ inline unsigned short f2bf(float f) {
    union { __bf16 b; unsigned short u; } v;
    v.b = (__bf16)f;                      // hw cvt (RTNE) on gfx950
    return v.u;
}
__device__ inline float bf2f(unsigned short u) {
    union { unsigned int u; float f; } v;
    v.u = (unsigned int)u << 16;
    return v.f;
}

// ---------------- Kernel 0: W prep — fragment-order B ----------------------
__global__ __launch_bounds__(256) void wprep(const float* __restrict__ Wq,
                                             const float* __restrict__ Wk,
                                             const float* __restrict__ Wv,
                                             unsigned short* __restrict__ wtf) {
    const int idx = blockIdx.x * 256 + threadIdx.x;
    if (idx >= NN * CC) return;
    const int j = idx & 7;
    const int lane = (idx >> 3) & 63;
    const int rest = idx >> 9;              // 0..287
    const int kg = rest % 24;
    const int n_tile = rest / 24;
    const int c = kg * 32 + (lane >> 4) * 8 + j;
    const int n = n_tile * 16 + (lane & 15);
    const float* W = (n < 64) ? Wq : (n < 128) ? Wk : Wv;
    wtf[idx] = f2bf(W[c * HH + (n & 63)]);
}

// ---------------- Kernel 1: fused QKV projection MFMA GEMM (R8, proven) -----
__global__ __launch_bounds__(256) void qkv_gemm(const float* __restrict__ x,
                                                const unsigned short* __restrict__ wtf,
                                                unsigned short* __restrict__ qb,
                                                unsigned short* __restrict__ kb,
                                                unsigned short* __restrict__ vbt) {
    __shared__ unsigned short As[GR * XSTR];  // 48.5 KB

    const int tid = threadIdx.x;
    const int w = tid >> 6, lane = tid & 63;
    const int l15 = lane & 15, quad = lane >> 4;
    const int m0 = blockIdx.x * GR;
    const int n0 = w * 48;
    const int nt0 = w * 3;

    const float* xbase = x + (size_t)m0 * CC;
#pragma unroll
    for (int e = 0; e < 12; ++e) {
        const int c = tid + 256 * e;          // 0..3071
        const int r = c / 96, off = (c - r * 96) * 8;
        const float4 v0 = *(const float4*)(xbase + (size_t)c * 8);
        const float4 v1 = *(const float4*)(xbase + (size_t)c * 8 + 4);
        u16x8 pk;
        pk[0] = f2bf(v0.x); pk[1] = f2bf(v0.y); pk[2] = f2bf(v0.z); pk[3] = f2bf(v0.w);
        pk[4] = f2bf(v1.x); pk[5] = f2bf(v1.y); pk[6] = f2bf(v1.z); pk[7] = f2bf(v1.w);
        *(u16x8*)(As + r * XSTR + off) = pk;
    }
    __syncthreads();                          // the ONLY barrier

    floatx4 acc[2][3] = {};
#pragma unroll 4
    for (int step = 0; step < 12; ++step) {
        bf16x8 a0[2], a1[2];
#pragma unroll
        for (int rg = 0; rg < 2; ++rg) {
            const unsigned short* ap = As + (16 * rg + l15) * XSTR + step * 64 + quad * 8;
            a0[rg] = *(const bf16x8*)(ap);
            a1[rg] = *(const bf16x8*)(ap + 32);
        }
#pragma unroll
        for (int j = 0; j < 3; ++j) {
            const unsigned short* bp =
                wtf + ((size_t)((nt0 + j) * 24 + 2 * step) * 64 + lane) * 8;
            const bf16x8 b0 = *(const bf16x8*)(bp);
            const bf16x8 b1 = *(const bf16x8*)(bp + 512);
#pragma unroll
            for (int rg = 0; rg < 2; ++rg) {
                acc[rg][j] = __builtin_amdgcn_mfma_f32_16x16x32_bf16(a0[rg], b0, acc[rg][j], 0, 0, 0);
                acc[rg][j] = __builtin_amdgcn_mfma_f32_16x16x32_bf16(a1[rg], b1, acc[rg][j], 0, 0, 0);
            }
        }
    }

    const int b = m0 >> 12;
#pragma unroll
    for (int j = 0; j < 3; ++j) {
        const int n = n0 + j * 16 + l15;
        const int mid = n >> 6;                  // 0=Q,1=K,2=V
        const int h = n & 63;
#pragma unroll
        for (int rg = 0; rg < 2; ++rg) {
            const int tloc = (m0 & (TT - 1)) + 16 * rg + quad * 4;
            if (mid == 2) {
                ushort4 pk;
                pk.x = f2bf(acc[rg][j][0]); pk.y = f2bf(acc[rg][j][1]);
                pk.z = f2bf(acc[rg][j][2]); pk.w = f2bf(acc[rg][j][3]);
                *(ushort4*)(vbt + ((size_t)b * HH + h) * TT + tloc) = pk;
            } else {
                unsigned short* dst = (mid == 0) ? qb : kb;
#pragma unroll
                for (int r = 0; r < 4; ++r)
                    dst[(size_t)(m0 + 16 * rg + quad * 4 + r) * HH + h] = f2bf(acc[rg][j][r]);
            }
        }
    }
}

// ------------- Kernel 2a: flash attention phase 1 (split-K partials) --------
// R7 structure + (a) exp2 w/ folded scale, (b) bf16 partials (half write
// traffic), (c) single-chunk (qt<CH) fast path writes `out` directly.
template<int CH>
__global__ __launch_bounds__(256) void attn_part(const unsigned short* __restrict__ qb,
                                                 const unsigned short* __restrict__ kb,
                                                 const unsigned short* __restrict__ vbt,
                                                 unsigned short* __restrict__ Opart,
                                                 float* __restrict__ lsum,
                                                 float* __restrict__ out) {
    __shared__ unsigned short Ks[64 * LDP];
    __shared__ unsigned short VTs[64 * LDP];
    __shared__ unsigned short Ps[4][16 * LDP];

    constexpr int NG = 64 / CH;
    constexpr int TOTB = CH * (NG * (NG + 1)) / 2;

    const int b = blockIdx.x & 3;
    int rem = TOTB - 1 - (blockIdx.x >> 2);           // heavy-first
    int g = 0;
    while (rem >= CH * (g + 1)) { rem -= CH * (g + 1); ++g; }
    const int qt = g * CH + rem / (g + 1);
    const int ch = rem - (rem / (g + 1)) * (g + 1);

    const int q0  = qt * 64;
    const int tid = threadIdx.x;
    const int w = tid >> 6, lane = tid & 63;
    const int l15 = lane & 15, quad = lane >> 4;

    const unsigned short* Qb  = qb  + (size_t)b * TT * HH;
    const unsigned short* Kb  = kb  + (size_t)b * TT * HH;
    const unsigned short* VTb = vbt + (size_t)b * HH * TT;

    const int qrow = q0 + 16 * w + l15;
    const bf16x8 qf0 = *(const bf16x8*)(Qb + (size_t)qrow * HH + quad * 8);
    const bf16x8 qf1 = *(const bf16x8*)(Qb + (size_t)qrow * HH + 32 + quad * 8);

    floatx4 O[4] = {};
    floatx4 lacc = {0.f, 0.f, 0.f, 0.f};

    const int kt0 = ch * CH;
    const int kt1 = min(kt0 + CH, qt + 1);
    for (int kt = kt0; kt < kt1; ++kt) {
        __syncthreads();
        const unsigned short* Kt = Kb + (size_t)(kt * 64) * HH;
        const unsigned short* Vt = VTb + kt * 64;
#pragma unroll
        for (int e = 0; e < 2; ++e) {
            const int chunk = tid + 256 * e;
            const int r = chunk >> 3, c0 = (chunk & 7) * 8;
            *(u16x8*)(Ks + r * LDP + c0)  = *(const u16x8*)(Kt + r * HH + c0);
            *(u16x8*)(VTs + r * LDP + c0) = *(const u16x8*)(Vt + (size_t)r * TT + c0);
        }
        __syncthreads();

        floatx4 s[4];
#pragma unroll
        for (int ki = 0; ki < 4; ++ki) {
            const bf16x8 kf0 = *(const bf16x8*)(Ks + (16 * ki + l15) * LDP + quad * 8);
            const bf16x8 kf1 = *(const bf16x8*)(Ks + (16 * ki + l15) * LDP + 32 + quad * 8);
            floatx4 c = {};
            c = __builtin_amdgcn_mfma_f32_16x16x32_bf16(qf0, kf0, c, 0, 0, 0);
            c = __builtin_amdgcn_mfma_f32_16x16x32_bf16(qf1, kf1, c, 0, 0, 0);
            s[ki] = c * SC2;                  // scale * log2(e); exp2 below
        }

        if (kt == qt) {
#pragma unroll
            for (int ki = 0; ki < 4; ++ki)
#pragma unroll
                for (int r = 0; r < 4; ++r) {
                    const int kloc = 16 * ki + l15;
                    const int qloc = 16 * w + quad * 4 + r;
                    if (kloc > qloc) s[ki][r] = -INFINITY;
                }
        }

#pragma unroll
        for (int ki = 0; ki < 4; ++ki)
#pragma unroll
            for (int r = 0; r < 4; ++r) {
                const float p = exp2f(s[ki][r]);   // == exp(raw_s); exp2(-inf)=0
                s[ki][r] = p;
                lacc[r] += p;
            }

        unsigned short* Pw = Ps[w];
#pragma unroll
        for (int ki = 0; ki < 4; ++ki)
#pragma unroll
            for (int r = 0; r < 4; ++r)
                Pw[(quad * 4 + r) * LDP + 16 * ki + l15] = f2bf(s[ki][r]);

        const bf16x8 pf0 = *(const bf16x8*)(Pw + l15 * LDP + quad * 8);
        const bf16x8 pf1 = *(const bf16x8*)(Pw + l15 * LDP + 32 + quad * 8);
#pragma unroll
        for (int di = 0; di < 4; ++di) {
            const bf16x8 vf0 = *(const bf16x8*)(VTs + (16 * di + l15) * LDP + quad * 8);
            const bf16x8 vf1 = *(const bf16x8*)(VTs + (16 * di + l15) * LDP + 32 + quad * 8);
            O[di] = __builtin_amdgcn_mfma_f32_16x16x32_bf16(pf0, vf0, O[di], 0, 0, 0);
            O[di] = __builtin_amdgcn_mfma_f32_16x16x32_bf16(pf1, vf1, O[di], 0, 0, 0);
        }
    }

    float l_r[4];
#pragma unroll
    for (int r = 0; r < 4; ++r) {
        float v = lacc[r];
#pragma unroll
        for (int msk = 8; msk >= 1; msk >>= 1) v += __shfl_xor(v, msk, 64);
        l_r[r] = v;
    }

    if (qt < CH) {
        // single-chunk q-tile: normalize and write out directly (merge skips)
        float* outp = out + ((size_t)b * TT + q0 + 16 * w) * HH;
#pragma unroll
        for (int di = 0; di < 4; ++di)
#pragma unroll
            for (int r = 0; r < 4; ++r)
                outp[(quad * 4 + r) * HH + 16 * di + l15] = O[di][r] / l_r[r];
        return;
    }

    const int pbase = ((b * 64 + qt) * NG + ch) * 64;
    unsigned short* Op = Opart + (size_t)pbase * HH + 16 * w * HH;
#pragma unroll
    for (int di = 0; di < 4; ++di)
#pragma unroll
        for (int r = 0; r < 4; ++r)
            Op[(quad * 4 + r) * HH + 16 * di + l15] = f2bf(O[di][r]);
    if (l15 == 0) {
#pragma unroll
        for (int r = 0; r < 4; ++r)
            lsum[pbase + 16 * w + quad * 4 + r] = l_r[r];
    }
}

// ------------- Kernel 2b: merge partials (bf16, vectorized) -----------------
// Thread per (row, 8-dim octet): u16x8 partial loads, float4 stores.
// Rows with qt < CH were written directly by attn_part -> skip.
template<int CH>
__global__ __launch_bounds__(256) void attn_merge(const unsigned short* __restrict__ Opart,
                                                  const float* __restrict__ lsum,
                                                  float* __restrict__ out) {
    constexpr int NG = 64 / CH;
    const int g = blockIdx.x * 256 + threadIdx.x;   // row*8 + octet
    const int row = g >> 3, oct = g & 7;
    const int b = row >> 12, t = row & (TT - 1);
    const int qt = t >> 6, rloc = t & 63;
    if (qt < CH) return;                            // fast-path rows done
    const int nchunk = qt / CH + 1;
    const int pbase = ((b * 64 + qt) * NG) * 64 + rloc;
    const int d0 = oct * 8;

    float L = 0.f;
    float a[8] = {};
    for (int c = 0; c < nchunk; ++c) {
        const int idx = pbase + c * 64;
        L += lsum[idx];
        const u16x8 pv = *(const u16x8*)(Opart + (size_t)idx * HH + d0);
#pragma unroll
        for (int k = 0; k < 8; ++k) a[k] += bf2f(pv[k]);
    }
    const float inv = 1.f / L;
    float4 o0, o1;
    o0.x = a[0] * inv; o0.y = a[1] * inv; o0.z = a[2] * inv; o0.w = a[3] * inv;
    o1.x = a[4] * inv; o1.y = a[5] * inv; o1.z = a[6] * inv; o1.w = a[7] * inv;
    float* dst = out + (size_t)row * HH + d0;
    *(float4*)(dst) = o0;
    *(float4*)(dst + 4) = o1;
}

// ------------- Fallback: single-pass attention ------------------------------
__global__ __launch_bounds__(256) void attn_full(const unsigned short* __restrict__ qb,
                                                 const unsigned short* __restrict__ kb,
                                                 const unsigned short* __restrict__ vbt,
                                                 float* __restrict__ out) {
    __shared__ unsigned short Ks[64 * LDP];
    __shared__ unsigned short VTs[64 * LDP];
    __shared__ unsigned short Ps[4][16 * LDP];

    const int b   = blockIdx.x >> 6;
    const int qt  = blockIdx.x & 63;
    const int q0  = qt * 64;
    const int tid = threadIdx.x;
    const int w = tid >> 6, lane = tid & 63;
    const int l15 = lane & 15, quad = lane >> 4;

    const unsigned short* Qb  = qb  + (size_t)b * TT * HH;
    const unsigned short* Kb  = kb  + (size_t)b * TT * HH;
    const unsigned short* VTb = vbt + (size_t)b * HH * TT;

    const int qrow = q0 + 16 * w + l15;
    const bf16x8 qf0 = *(const bf16x8*)(Qb + (size_t)qrow * HH + quad * 8);
    const bf16x8 qf1 = *(const bf16x8*)(Qb + (size_t)qrow * HH + 32 + quad * 8);

    floatx4 O[4] = {};
    floatx4 lacc = {0.f, 0.f, 0.f, 0.f};

    for (int kt = 0; kt <= qt; ++kt) {
        __syncthreads();
        const unsigned short* Kt = Kb + (size_t)(kt * 64) * HH;
        const unsigned short* Vt = VTb + kt * 64;
#pragma unroll
        for (int e = 0; e < 2; ++e) {
            const int chunk = tid + 256 * e;
            const int r = chunk >> 3, c0 = (chunk & 7) * 8;
            *(u16x8*)(Ks + r * LDP + c0)  = *(const u16x8*)(Kt + r * HH + c0);
            *(u16x8*)(VTs + r * LDP + c0) = *(const u16x8*)(Vt + (size_t)r * TT + c0);
        }
        __syncthreads();

        floatx4 s[4];
#pragma unroll
        for (int ki = 0; ki < 4; ++ki) {
            const bf16x8 kf0 = *(const bf16x8*)(Ks + (16 * ki + l15) * LDP + quad * 8);
            const bf16x8 kf1 = *(const bf16x8*)(Ks + (16 * ki + l15) * LDP + 32 + quad * 8);
            floatx4 c = {};
            c = __builtin_amdgcn_mfma_f32_16x16x32_bf16(qf0, kf0, c, 0, 0, 0);
            c = __builtin_amdgcn_mfma_f32_16x16x32_bf16(qf1, kf1, c, 0, 0, 0);
            s[ki] = c * SC2;
        }
        if (kt == qt) {
#pragma unroll
            for (int ki = 0; ki < 4; ++ki)
#pragma unroll
                for (int r = 0; r < 4; ++r)
                    if (16 * ki + l15 > 16 * w + quad * 4 + r) s[ki][r] = -INFINITY;
        }
#pragma unroll
        for (int ki = 0; ki < 4; ++ki)
#pragma unroll
            for (int r = 0; r < 4; ++r) {
                const float p = exp2f(s[ki][r]);
                s[ki][r] = p; lacc[r] += p;
            }

        unsigned short* Pw = Ps[w];
#pragma unroll
        for (int ki = 0; ki < 4; ++ki)
#pragma unroll
            for (int r = 0; r < 4; ++r)
                Pw[(quad * 4 + r) * LDP + 16 * ki + l15] = f2bf(s[ki][r]);

        const bf16x8 pf0 = *(const bf16x8*)(Pw + l15 * LDP + quad * 8);
        const bf16x8 pf1 = *(const bf16x8*)(Pw + l15 * LDP + 32 + quad * 8);
#pragma unroll
        for (int di = 0; di < 4; ++di) {
            const bf16x8 vf0 = *(const bf16x8*)(VTs + (16 * di + l15) * LDP + quad * 8);
            const bf16x8 vf1 = *(const bf16x8*)(VTs + (16 * di + l15) * LDP + 32 + quad * 8);
            O[di] = __builtin_amdgcn_mfma_f32_16x16x32_bf16(pf0, vf0, O[di], 0, 0, 0);
            O[di] = __builtin_amdgcn_mfma_f32_16x16x32_bf16(pf1, vf1, O[di], 0, 0, 0);
        }
    }
    float l_r[4];
#pragma unroll
    for (int r = 0; r < 4; ++r) {
        float v = lacc[r];
#pragma unroll
        for (int msk = 8; msk >= 1; msk >>= 1) v += __shfl_xor(v, msk, 64);
        l_r[r] = v;
    }
    float* outp = out + ((size_t)b * TT + q0 + 16 * w) * HH;
#pragma unroll
    for (int di = 0; di < 4; ++di)
#pragma unroll
        for (int r = 0; r < 4; ++r)
            outp[(quad * 4 + r) * HH + 16 * di + l15] = O[di][r] / l_r[r];
}

extern "C" void kernel_launch(void* const* d_in, const int* in_sizes, int n_in,
                              void* d_out, int out_size, void* d_ws, size_t ws_size,
                              hipStream_t stream) {
    const float* x  = (const float*)d_in[0];
    const float* Wq = (const float*)d_in[1];
    const float* Wk = (const float*)d_in[2];
    const float* Wv = (const float*)d_in[3];
    float* out = (float*)d_out;

    const size_t nQKV = (size_t)BB * TT * HH;           // 1 Mi elems
    unsigned short* qb  = (unsigned short*)d_ws;
    unsigned short* kb  = qb + nQKV;
    unsigned short* vbt = kb + nQKV;
    unsigned short* wtf = vbt + nQKV;                   // NN*CC ushorts
    unsigned short* Opart = wtf + (size_t)NN * CC;      // bf16 partials

    const size_t prows8  = (size_t)BB * 64 * 8 * 64;
    const size_t prows16 = (size_t)BB * 64 * 4 * 64;
    float* lsum8  = (float*)(Opart + prows8 * HH);
    float* lsum16 = (float*)(Opart + prows16 * HH);
    const size_t need8  = (size_t)((char*)(lsum8  + prows8)  - (char*)d_ws);
    const size_t need16 = (size_t)((char*)(lsum16 + prows16) - (char*)d_ws);

    wprep<<<(NN * CC + 255) / 256, 256, 0, stream>>>(Wq, Wk, Wv, wtf);
    qkv_gemm<<<(BB * TT) / GR, 256, 0, stream>>>(x, wtf, qb, kb, vbt);
    if (ws_size >= need8) {
        attn_part<8><<<BB * 288, 256, 0, stream>>>(qb, kb, vbt, Opart, lsum8, out);
        attn_merge<8><<<(BB * TT * 8) / 256, 256, 0, stream>>>(Opart, lsum8, out);
    } else if (ws_size >= need16) {
        attn_part<16><<<BB * 160, 256, 0, stream>>>(qb, kb, vbt, Opart, lsum16, out);
        attn_merge<16><<<(BB * TT * 8) / 256, 256, 0, stream>>>(Opart, lsum16, out);
    } else {
        attn_full<<<BB * (TT / 64), 256, 0, stream>>>(qb, kb, vbt, out);
    }
}